// Round 11
// baseline (46.248 us; speedup 1.0000x reference)
//
#include <hip/hip_runtime.h>

#define B 2
#define S 512
#define D 256
#define C2L 2.885390081777927f    // 2*log2(e)
#define LOG2E 1.4426950408889634f

typedef float f32x2 __attribute__((ext_vector_type(2)));

// proj: Pt = (q @ W^T) * C2L.
//   EJ4[b][e>>2][i][e&3] = exp2(Pt)  (float4-over-e: score loads dwordx4, coalesced)
//   EN[b][i][e] = exp2(-Pt)          (row-major: fused kernel row factors)
__global__ __launch_bounds__(256) void proj_kernel(const float* __restrict__ q,
                                                   const float* __restrict__ W,
                                                   float* __restrict__ EJ4,
                                                   float* __restrict__ EN) {
    __shared__ float qlds[4 * D];
    const int t = threadIdx.x;
    const int b = blockIdx.x / (S / 4);
    const int i0 = (blockIdx.x % (S / 4)) * 4;
    const float* qbase = q + (size_t)(b * S + i0) * D;
    for (int idx = t; idx < 4 * D; idx += 256) qlds[idx] = qbase[idx];
    __syncthreads();
    const float* wr = W + (size_t)t * D;
    float a0 = 0.f, a1 = 0.f, a2 = 0.f, a3 = 0.f;
#pragma unroll 4
    for (int d = 0; d < D; ++d) {
        float w = wr[d];
        a0 = fmaf(qlds[d], w, a0);
        a1 = fmaf(qlds[D + d], w, a1);
        a2 = fmaf(qlds[2 * D + d], w, a2);
        a3 = fmaf(qlds[3 * D + d], w, a3);
    }
    a0 *= C2L; a1 *= C2L; a2 *= C2L; a3 *= C2L;
    float* ejb = EJ4 + (((size_t)(b * 64 + (t >> 2))) * S + i0) * 4 + (t & 3);
    ejb[0]  = __builtin_amdgcn_exp2f(a0);
    ejb[4]  = __builtin_amdgcn_exp2f(a1);
    ejb[8]  = __builtin_amdgcn_exp2f(a2);
    ejb[12] = __builtin_amdgcn_exp2f(a3);
    EN[(size_t)(b * S + i0 + 0) * D + t] = __builtin_amdgcn_exp2f(-a0);
    EN[(size_t)(b * S + i0 + 1) * D + t] = __builtin_amdgcn_exp2f(-a1);
    EN[(size_t)(b * S + i0 + 2) * D + t] = __builtin_amdgcn_exp2f(-a2);
    EN[(size_t)(b * S + i0 + 3) * D + t] = __builtin_amdgcn_exp2f(-a3);
}

// Fused score + softmax + context. Block = 4 rows, 512 threads, thread t = col j.
// Score loop: explicit 8-deep global prefetch (evb rotation, static indices) +
// paired reciprocals: rows (0,2) share ONE hw rcp (r=rcp(y0*y2); s0=r*y2, s2=r*y0),
// rows (1,3) share one magic+Newton rcp on the VALU pipe. Products <= 2^90: safe.
__global__ __launch_bounds__(512, 2) void fused_kernel(const float* __restrict__ EJ4,
                                                       const float* __restrict__ EN,
                                                       const float* __restrict__ vm,
                                                       const float* __restrict__ value,
                                                       float* __restrict__ att,
                                                       float* __restrict__ ctx) {
    __shared__ float enw[D][8];          // {f_r0, f_r2, f_r1, f_r3, -2vm, pad...}
    __shared__ float a4[S][4];           // normalized attention rows
    __shared__ float part[4][8][64][4];  // ctx partials
    __shared__ float redm[4][8], reds[4][8];

    const int t = threadIdx.x;
    const int b = blockIdx.x >> 7;           // S/4 = 128 blocks per batch
    const int i0 = (blockIdx.x & 127) * 4;

    {   // stage row factors: rows (0,2)->slots(0,1) [HW rcp], (1,3)->slots(2,3) [Newton]
        const int e = t & 255, r = t >> 8;   // r=0: rows i0,i0+1 ; r=1: rows i0+2,i0+3
        const int row0 = i0 + 2 * r;         // handles rows 2r and 2r+1
        const int slot0 = r;                 // row 2r -> slot r  (0->0, 1->1)
        const int slot1 = 2 + r;             // row 2r+1 -> slot 2+r (1->2, 3->3)
        enw[e][slot0] = EN[((size_t)(b * S + row0)) * D + e];
        enw[e][slot1] = EN[((size_t)(b * S + row0 + 1)) * D + e];
        if (r == 0) enw[e][4] = -2.f * vm[e];
    }
    __syncthreads();

    // ---- score: s'[r] = sum_e (-2 vm_e) * sigma(2(Pj - Pr))  (shift cancels)
    const float4* ejp = (const float4*)EJ4 + (size_t)b * 64 * S + t;
    float4 evb[8];
#pragma unroll
    for (int k = 0; k < 8; ++k) evb[k] = ejp[(size_t)k * S];

    f32x2 acc02 = {0.f, 0.f}, acc13 = {0.f, 0.f};
#pragma unroll 1
    for (int go = 0; go < 64; go += 8) {
#pragma unroll
        for (int k = 0; k < 8; ++k) {
            float4 ev4 = evb[k];
            // refill slot for group go+8+k; over-read past EJ4 lands in EN (safe)
            evb[k] = ejp[(size_t)(go + 8 + k) * S];
#pragma unroll
            for (int c = 0; c < 4; ++c) {
                const float ev = (c == 0) ? ev4.x : (c == 1) ? ev4.y
                               : (c == 2) ? ev4.z : ev4.w;
                const int e = (go + k) * 4 + c;
                float4 f = *(const float4*)&enw[e][0];
                const float w = enw[e][4];
                f32x2 ev2 = {ev, ev};
                f32x2 f02 = {f.x, f.y}, f13 = {f.z, f.w};
                f32x2 one2 = {1.f, 1.f};
                f32x2 y02 = ev2 * f02 + one2;          // y_r0, y_r2
                f32x2 y13 = ev2 * f13 + one2;          // y_r1, y_r3
                float m02 = y02.x * y02.y;
                float m13 = y13.x * y13.y;
                float r02 = __builtin_amdgcn_rcpf(m02);                 // trans pipe
                float rn = __uint_as_float(0x7EF311C3u - __float_as_uint(m13));
                rn = rn * fmaf(-m13, rn, 2.f);                          // VALU pipe
                rn = rn * fmaf(-m13, rn, 2.f);
                f32x2 s02 = {r02 * y02.y, r02 * y02.x};
                f32x2 s13 = {rn * y13.y, rn * y13.x};
                f32x2 w2 = {w, w};
                acc02 += w2 * s02;
                acc13 += w2 * s13;
            }
        }
    }
    // slots: acc02 = rows (i0, i0+2), acc13 = rows (i0+1, i0+3)
    float accR[4] = {acc02.x, acc13.x, acc02.y, acc13.y};

    // ---- softmax over j (one value per thread per row, 8 waves)
    const int lane = t & 63, wv = t >> 6;
#pragma unroll
    for (int r = 0; r < 4; ++r) {
        float lm = accR[r];
#pragma unroll
        for (int off = 32; off; off >>= 1) lm = fmaxf(lm, __shfl_xor(lm, off));
        if (lane == 0) redm[r][wv] = lm;
    }
    __syncthreads();
    float p[4];
#pragma unroll
    for (int r = 0; r < 4; ++r) {
        float m = redm[r][0];
#pragma unroll
        for (int w = 1; w < 8; ++w) m = fmaxf(m, redm[r][w]);
        p[r] = __builtin_amdgcn_exp2f((accR[r] - m) * LOG2E);
        float ls = p[r];
#pragma unroll
        for (int off = 32; off; off >>= 1) ls += __shfl_xor(ls, off);
        if (lane == 0) reds[r][wv] = ls;
    }
    __syncthreads();
#pragma unroll
    for (int r = 0; r < 4; ++r) {
        float s = 0.f;
#pragma unroll
        for (int w = 0; w < 8; ++w) s += reds[r][w];
        float a = p[r] * __builtin_amdgcn_rcpf(s);
        a4[t][r] = a;
        att[(size_t)(b * S + i0 + r) * S + t] = a;
    }
    __syncthreads();

    // ---- context: thread -> (dq = t&63, js = t>>6); value read once per block
    {
        const int dq = t & 63, js = t >> 6;
        float4 acc0 = {}, acc1 = {}, acc2 = {}, acc3 = {};
        const float* vb = value + (size_t)b * S * D + (size_t)dq * 4;
#pragma unroll 4
        for (int jj = 0; jj < 64; ++jj) {
            int jx = js * 64 + jj;
            float4 v = *(const float4*)(vb + (size_t)jx * D);
            float w0 = a4[jx][0], w1 = a4[jx][1], w2 = a4[jx][2], w3 = a4[jx][3];
            acc0.x = fmaf(w0, v.x, acc0.x); acc0.y = fmaf(w0, v.y, acc0.y);
            acc0.z = fmaf(w0, v.z, acc0.z); acc0.w = fmaf(w0, v.w, acc0.w);
            acc1.x = fmaf(w1, v.x, acc1.x); acc1.y = fmaf(w1, v.y, acc1.y);
            acc1.z = fmaf(w1, v.z, acc1.z); acc1.w = fmaf(w1, v.w, acc1.w);
            acc2.x = fmaf(w2, v.x, acc2.x); acc2.y = fmaf(w2, v.y, acc2.y);
            acc2.z = fmaf(w2, v.z, acc2.z); acc2.w = fmaf(w2, v.w, acc2.w);
            acc3.x = fmaf(w3, v.x, acc3.x); acc3.y = fmaf(w3, v.y, acc3.y);
            acc3.z = fmaf(w3, v.z, acc3.z); acc3.w = fmaf(w3, v.w, acc3.w);
        }
        *(float4*)&part[0][js][dq][0] = acc0;
        *(float4*)&part[1][js][dq][0] = acc1;
        *(float4*)&part[2][js][dq][0] = acc2;
        *(float4*)&part[3][js][dq][0] = acc3;
    }
    __syncthreads();
    if (t < 256) {
        const int row = t >> 6, dq = t & 63;
        float4 sum = {};
#pragma unroll
        for (int js = 0; js < 8; ++js) {
            float4 pt = *(const float4*)&part[row][js][dq][0];
            sum.x += pt.x; sum.y += pt.y; sum.z += pt.z; sum.w += pt.w;
        }
        *(float4*)(ctx + (size_t)(b * S + i0 + row) * D + (size_t)dq * 4) = sum;
    }
}

extern "C" void kernel_launch(void* const* d_in, const int* in_sizes, int n_in,
                              void* d_out, int out_size, void* d_ws, size_t ws_size,
                              hipStream_t stream) {
    const float* q = (const float*)d_in[0];
    // d_in[1] = key (unused by the reference)
    const float* value = (const float*)d_in[2];
    const float* W = (const float*)d_in[3];
    const float* vm = (const float*)d_in[4];

    float* ctx = (float*)d_out;                    // [B,S,D]
    float* att = ctx + (size_t)B * S * D;          // [B,S,S]
    float* EJ4 = (float*)d_ws;                     // [B][64][S][4] exp2(Pt), 1 MB
    float* EN = EJ4 + (size_t)B * D * S;           // [B,S,D] exp2(-Pt), 1 MB
                                                   // (EJ4 prefetch over-reads into EN: safe)

    proj_kernel<<<B * (S / 4), 256, 0, stream>>>(q, W, EJ4, EN);
    fused_kernel<<<B * (S / 4), 512, 0, stream>>>(EJ4, EN, vm, value, att, ctx);
}

// Round 12
// 42.490 us; speedup vs baseline: 1.0884x; 1.0884x over previous
//
#include <hip/hip_runtime.h>

#define B 2
#define S 512
#define D 256
#define C2L 2.885390081777927f    // 2*log2(e)
#define LOG2E 1.4426950408889634f

// proj: Pt = (q @ W^T) * C2L.
//   EJ4[b][e>>2][i][e&3] = exp2(Pt)  (float4-over-e: score loads dwordx4, coalesced)
//   EN[b][i][e] = exp2(-Pt)          (row-major; consumed via SCALAR s_load in fused)
//   W2[e] = -2*vm[e]                 (scalar-load stream)
__global__ __launch_bounds__(256) void proj_kernel(const float* __restrict__ q,
                                                   const float* __restrict__ W,
                                                   const float* __restrict__ vm,
                                                   float* __restrict__ EJ4,
                                                   float* __restrict__ EN,
                                                   float* __restrict__ W2) {
    __shared__ float qlds[4 * D];
    const int t = threadIdx.x;
    const int b = blockIdx.x / (S / 4);
    const int i0 = (blockIdx.x % (S / 4)) * 4;
    if (blockIdx.x == 0) W2[t] = -2.f * vm[t];
    const float* qbase = q + (size_t)(b * S + i0) * D;
    for (int idx = t; idx < 4 * D; idx += 256) qlds[idx] = qbase[idx];
    __syncthreads();
    const float* wr = W + (size_t)t * D;
    float a0 = 0.f, a1 = 0.f, a2 = 0.f, a3 = 0.f;
#pragma unroll 4
    for (int d = 0; d < D; ++d) {
        float w = wr[d];
        a0 = fmaf(qlds[d], w, a0);
        a1 = fmaf(qlds[D + d], w, a1);
        a2 = fmaf(qlds[2 * D + d], w, a2);
        a3 = fmaf(qlds[3 * D + d], w, a3);
    }
    a0 *= C2L; a1 *= C2L; a2 *= C2L; a3 *= C2L;
    float* ejb = EJ4 + (((size_t)(b * 64 + (t >> 2))) * S + i0) * 4 + (t & 3);
    ejb[0]  = __builtin_amdgcn_exp2f(a0);
    ejb[4]  = __builtin_amdgcn_exp2f(a1);
    ejb[8]  = __builtin_amdgcn_exp2f(a2);
    ejb[12] = __builtin_amdgcn_exp2f(a3);
    EN[(size_t)(b * S + i0 + 0) * D + t] = __builtin_amdgcn_exp2f(-a0);
    EN[(size_t)(b * S + i0 + 1) * D + t] = __builtin_amdgcn_exp2f(-a1);
    EN[(size_t)(b * S + i0 + 2) * D + t] = __builtin_amdgcn_exp2f(-a2);
    EN[(size_t)(b * S + i0 + 3) * D + t] = __builtin_amdgcn_exp2f(-a3);
}

// Fused score + softmax + context. Block = 2 rows, 512 threads, thread t = col j.
// Score loop has ZERO LDS and zero VALU operand fetch: row factors f0,f1 and
// weights w are block-uniform -> compiler scalarizes to s_load_dwordx4 (SMEM
// pipe, SGPR sources). One HW rcp serves both rows: r=rcp(y0*y1), s0=r*y1,
// s1=r*y0. Per e: 7 VALU + 1 trans. Products <= 2^58: finite, no denormal risk.
__global__ __launch_bounds__(512, 2) void fused_kernel(const float* __restrict__ EJ4,
                                                       const float* __restrict__ EN,
                                                       const float* __restrict__ W2,
                                                       const float* __restrict__ value,
                                                       float* __restrict__ att,
                                                       float* __restrict__ ctx) {
    __shared__ float a2s[S][2];          // normalized attention rows
    __shared__ float part[2][8][64][4];  // ctx partials
    __shared__ float redm[2][8], reds[2][8];

    const int t = threadIdx.x;
    const int b = blockIdx.x >> 8;           // S/2 = 256 blocks per batch
    const int i0 = (blockIdx.x & 255) * 2;

    // ---- score: s'[r] = sum_e (-2 vm_e) * sigma(2(Pj - Pr))  (shift cancels)
    const float4* ejp = (const float4*)EJ4 + (size_t)b * 64 * S + t;
    const float4* f0p = (const float4*)(EN + ((size_t)(b * S + i0)) * D);      // uniform
    const float4* f1p = (const float4*)(EN + ((size_t)(b * S + i0 + 1)) * D);  // uniform
    const float4* wp  = (const float4*)W2;                                     // uniform

    float acc0 = 0.f, acc1 = 0.f;
#pragma unroll 4
    for (int g = 0; g < 64; ++g) {
        float4 ev4 = ejp[(size_t)g * S];   // vector load, coalesced (1 KB/wave)
        float4 f0 = f0p[g];                // s_load_dwordx4
        float4 f1 = f1p[g];                // s_load_dwordx4
        float4 wv = wp[g];                 // s_load_dwordx4
#pragma unroll
        for (int c = 0; c < 4; ++c) {
            const float ev = (c == 0) ? ev4.x : (c == 1) ? ev4.y
                           : (c == 2) ? ev4.z : ev4.w;
            const float fa = (c == 0) ? f0.x : (c == 1) ? f0.y
                           : (c == 2) ? f0.z : f0.w;
            const float fb = (c == 0) ? f1.x : (c == 1) ? f1.y
                           : (c == 2) ? f1.z : f1.w;
            const float w  = (c == 0) ? wv.x : (c == 1) ? wv.y
                           : (c == 2) ? wv.z : wv.w;
            float y0 = fmaf(ev, fa, 1.f);
            float y1 = fmaf(ev, fb, 1.f);
            float r  = __builtin_amdgcn_rcpf(y0 * y1);   // one trans op, both rows
            acc0 = fmaf(w * y1, r, acc0);
            acc1 = fmaf(w * y0, r, acc1);
        }
    }

    // ---- softmax over j (one value per thread per row, 8 waves)
    const int lane = t & 63, wv8 = t >> 6;
    {
        float lm0 = acc0, lm1 = acc1;
#pragma unroll
        for (int off = 32; off; off >>= 1) {
            lm0 = fmaxf(lm0, __shfl_xor(lm0, off));
            lm1 = fmaxf(lm1, __shfl_xor(lm1, off));
        }
        if (lane == 0) { redm[0][wv8] = lm0; redm[1][wv8] = lm1; }
    }
    __syncthreads();
    float m0 = redm[0][0], m1 = redm[1][0];
#pragma unroll
    for (int w = 1; w < 8; ++w) {
        m0 = fmaxf(m0, redm[0][w]);
        m1 = fmaxf(m1, redm[1][w]);
    }
    float p0 = __builtin_amdgcn_exp2f((acc0 - m0) * LOG2E);
    float p1 = __builtin_amdgcn_exp2f((acc1 - m1) * LOG2E);
    {
        float ls0 = p0, ls1 = p1;
#pragma unroll
        for (int off = 32; off; off >>= 1) {
            ls0 += __shfl_xor(ls0, off);
            ls1 += __shfl_xor(ls1, off);
        }
        if (lane == 0) { reds[0][wv8] = ls0; reds[1][wv8] = ls1; }
    }
    __syncthreads();
    float s0 = 0.f, s1 = 0.f;
#pragma unroll
    for (int w = 0; w < 8; ++w) { s0 += reds[0][w]; s1 += reds[1][w]; }
    float a0 = p0 * __builtin_amdgcn_rcpf(s0);
    float a1 = p1 * __builtin_amdgcn_rcpf(s1);
    a2s[t][0] = a0;
    a2s[t][1] = a1;
    att[(size_t)(b * S + i0) * S + t] = a0;
    att[(size_t)(b * S + i0 + 1) * S + t] = a1;
    __syncthreads();

    // ---- context: thread -> (dq = t&63, js = t>>6); value read once per block
    {
        const int dq = t & 63, js = t >> 6;
        float4 c0 = {}, c1 = {};
        const float* vb = value + (size_t)b * S * D + (size_t)dq * 4;
#pragma unroll 4
        for (int jj = 0; jj < 64; ++jj) {
            int jx = js * 64 + jj;
            float4 v = *(const float4*)(vb + (size_t)jx * D);
            float w0 = a2s[jx][0], w1 = a2s[jx][1];
            c0.x = fmaf(w0, v.x, c0.x); c0.y = fmaf(w0, v.y, c0.y);
            c0.z = fmaf(w0, v.z, c0.z); c0.w = fmaf(w0, v.w, c0.w);
            c1.x = fmaf(w1, v.x, c1.x); c1.y = fmaf(w1, v.y, c1.y);
            c1.z = fmaf(w1, v.z, c1.z); c1.w = fmaf(w1, v.w, c1.w);
        }
        *(float4*)&part[0][js][dq][0] = c0;
        *(float4*)&part[1][js][dq][0] = c1;
    }
    __syncthreads();
    if (t < 128) {
        const int row = t >> 6, dq = t & 63;
        float4 sum = {};
#pragma unroll
        for (int js = 0; js < 8; ++js) {
            float4 pt = *(const float4*)&part[row][js][dq][0];
            sum.x += pt.x; sum.y += pt.y; sum.z += pt.z; sum.w += pt.w;
        }
        *(float4*)(ctx + (size_t)(b * S + i0 + row) * D + (size_t)dq * 4) = sum;
    }
}

extern "C" void kernel_launch(void* const* d_in, const int* in_sizes, int n_in,
                              void* d_out, int out_size, void* d_ws, size_t ws_size,
                              hipStream_t stream) {
    const float* q = (const float*)d_in[0];
    // d_in[1] = key (unused by the reference)
    const float* value = (const float*)d_in[2];
    const float* W = (const float*)d_in[3];
    const float* vm = (const float*)d_in[4];

    float* ctx = (float*)d_out;                    // [B,S,D]
    float* att = ctx + (size_t)B * S * D;          // [B,S,S]
    float* EJ4 = (float*)d_ws;                     // [B][64][S][4] exp2(Pt), 1 MB
    float* EN = EJ4 + (size_t)B * D * S;           // [B,S,D] exp2(-Pt), 1 MB
    float* W2 = EN + (size_t)B * S * D;            // [D] -2*vm, 1 KB

    proj_kernel<<<B * (S / 4), 256, 0, stream>>>(q, W, vm, EJ4, EN, W2);
    fused_kernel<<<B * (S / 2), 512, 0, stream>>>(EJ4, EN, W2, value, att, ctx);
}